// Round 2
// baseline (266.656 us; speedup 1.0000x reference)
//
#include <hip/hip_runtime.h>
#include <hip/hip_bf16.h>

#define HH 8
#define DIN 512
#define HD 64
#define BB 16
#define NN 1024

typedef float f32x4 __attribute__((ext_vector_type(4)));
typedef short s16x8 __attribute__((ext_vector_type(8)));
typedef __bf16 bf16x8 __attribute__((ext_vector_type(8)));

__device__ __forceinline__ short f2bf(float f) {
  union { float f; unsigned u; } v; v.f = f;
  unsigned r = v.u + 0x7FFFu + ((v.u >> 16) & 1u);  // RNE
  return (short)(r >> 16);
}

__device__ __forceinline__ f32x4 mfma16(s16x8 a, s16x8 b, f32x4 c) {
  return __builtin_amdgcn_mfma_f32_16x16x32_bf16(
      __builtin_bit_cast(bf16x8, a), __builtin_bit_cast(bf16x8, b), c, 0, 0, 0);
}

// ---- mask dtype detection: 4-byte storage has byte(%4==1)==0 always ----
__global__ void k_detect(const unsigned char* __restrict__ m, int* __restrict__ flag) {
  const int t = threadIdx.x;
  const int nz = (m[4 * t + 1] != 0);
  unsigned long long b = __ballot(nz);
  __shared__ unsigned int anyv;
  if (t == 0) anyv = 0u;
  __syncthreads();
  if ((t & 63) == 0 && b) atomicOr(&anyv, 1u);
  __syncthreads();
  if (t == 0) flag[0] = (int)anyv;  // 1 = byte storage, 0 = 4-byte storage
}

// ---- pack mask to bits: bit=1 means masked (not allowed) ----
__global__ void k_packmask(const void* __restrict__ mask, const int* __restrict__ flag,
                           unsigned long long* __restrict__ words64) {
  const int i = blockIdx.x * 256 + threadIdx.x;
  int v;
  if (flag[0])
    v = (((const unsigned char*)mask)[i] != 0);
  else
    v = (((const int*)mask)[i] != 0);  // also correct for float 0.0/1.0 bit patterns
  unsigned long long b = __ballot(v);
  if ((threadIdx.x & 63) == 0) words64[i >> 6] = b;
}

// ---- fp32 -> bf16, 8 elems/thread ----
__global__ void k_f2bf8(const float* __restrict__ src, short* __restrict__ dst, int n8) {
  const int i = blockIdx.x * 256 + threadIdx.x;
  if (i >= n8) return;
  const float4* s4 = (const float4*)src;
  float4 a = s4[2 * i], c = s4[2 * i + 1];
  s16x8 o;
  o[0] = f2bf(a.x); o[1] = f2bf(a.y); o[2] = f2bf(a.z); o[3] = f2bf(a.w);
  o[4] = f2bf(c.x); o[5] = f2bf(c.y); o[6] = f2bf(c.z); o[7] = f2bf(c.w);
  ((s16x8*)dst)[i] = o;
}

// ---- QKV projection: C(16384 x 1536) = q_bf16(16384 x 512) @ [Wq|Wk|Wv] ----
// block: BM=128 x BN=64 (one head of one matrix), 4 waves, wave = 32 rows x 64 cols
__global__ __launch_bounds__(256) void k_proj(
    const s16x8* __restrict__ A8, const short* __restrict__ Wq,
    const short* __restrict__ Wk, const short* __restrict__ Wv,
    short* __restrict__ Qb, short* __restrict__ Kb, short* __restrict__ Vb) {
  __shared__ short ldsA[128 * 72];   // stride 72 (144B rows, 16B aligned, ~2-way banks)
  __shared__ short ldsBt[64 * 72];   // B transposed: Bt[n][k]
  const int tid = threadIdx.x;
  const int m0 = blockIdx.x * 128;
  const int j = blockIdx.y;
  const int mat = j >> 3, head = j & 7;
  const short* Wbase = (mat == 0 ? Wq : (mat == 1 ? Wk : Wv)) + head * (DIN * HD);
  short* Ob = (mat == 0 ? Qb : (mat == 1 ? Kb : Vb)) + head * (BB * NN * HD);
  const int w = tid >> 6, l = tid & 63, rowf = l & 15, kg = l >> 4;

  f32x4 acc[2][4];
#pragma unroll
  for (int qi = 0; qi < 2; ++qi)
#pragma unroll
    for (int cj = 0; cj < 4; ++cj) acc[qi][cj] = (f32x4){0.f, 0.f, 0.f, 0.f};

  for (int kt = 0; kt < DIN / 64; ++kt) {
    const int k0 = kt * 64;
    __syncthreads();
#pragma unroll
    for (int e = 0; e < 4; ++e) {  // A tile: 128x64 = 1024 8-elem chunks
      const int c = tid + e * 256;
      const int row = c >> 3, c8 = c & 7;
      *(s16x8*)&ldsA[row * 72 + c8 * 8] = A8[(m0 + row) * (DIN / 8) + (k0 >> 3) + c8];
    }
#pragma unroll
    for (int e = 0; e < 16; ++e) {  // B tile 64x64, transpose-stage
      const int f = tid + e * 256;
      const int k = f >> 6, n = f & 63;
      ldsBt[n * 72 + k] = Wbase[(k0 + k) * HD + n];
    }
    __syncthreads();

    s16x8 af[2][2], bfr[4][2];
#pragma unroll
    for (int qi = 0; qi < 2; ++qi)
#pragma unroll
      for (int kk = 0; kk < 2; ++kk)
        af[qi][kk] = *(const s16x8*)&ldsA[(w * 32 + qi * 16 + rowf) * 72 + kk * 32 + kg * 8];
#pragma unroll
    for (int cj = 0; cj < 4; ++cj)
#pragma unroll
      for (int kk = 0; kk < 2; ++kk)
        bfr[cj][kk] = *(const s16x8*)&ldsBt[(cj * 16 + rowf) * 72 + kk * 32 + kg * 8];
#pragma unroll
    for (int kk = 0; kk < 2; ++kk)
#pragma unroll
      for (int qi = 0; qi < 2; ++qi)
#pragma unroll
        for (int cj = 0; cj < 4; ++cj)
          acc[qi][cj] = mfma16(af[qi][kk], bfr[cj][kk], acc[qi][cj]);
  }

#pragma unroll
  for (int qi = 0; qi < 2; ++qi)
#pragma unroll
    for (int cj = 0; cj < 4; ++cj)
#pragma unroll
      for (int r = 0; r < 4; ++r) {
        const int m = m0 + w * 32 + qi * 16 + kg * 4 + r;  // C/D: row=(l>>4)*4+r, col=l&15
        Ob[(size_t)m * HD + cj * 16 + rowf] = f2bf(acc[qi][cj][r]);
      }
}

// ---- flash attention: block = (h,b,128 q-rows), 4 waves x 32 rows ----
__global__ __launch_bounds__(256) void k_attn(
    const short* __restrict__ Qb, const short* __restrict__ Kb, const short* __restrict__ Vb,
    const unsigned int* __restrict__ mw, short* __restrict__ heads) {
  __shared__ short ldsK[64 * 72];    // K tile row-major (B-frag = contiguous, no transpose)
  __shared__ short ldsVt[64 * 72];   // V transposed: Vt[v][k]
  __shared__ short ldsP[128 * 72];   // per-wave P rows
  const int tid = threadIdx.x;
  const int w = tid >> 6, l = tid & 63, rowf = l & 15, kg = l >> 4;
  const int qblk = blockIdx.x, b = blockIdx.y, h = blockIdx.z;
  const int hb = (h * BB + b) * NN;
  const short* Qp = Qb + (size_t)hb * HD;
  const short* Kp = Kb + (size_t)hb * HD;
  const short* Vp = Vb + (size_t)hb * HD;
  const int wq = qblk * 128 + w * 32;

  s16x8 aQ[2][2];  // Q stays in registers
#pragma unroll
  for (int qi = 0; qi < 2; ++qi)
#pragma unroll
    for (int kk = 0; kk < 2; ++kk)
      aQ[qi][kk] = *(const s16x8*)&Qp[(wq + qi * 16 + rowf) * HD + kk * 32 + kg * 8];

  float mrun[2][4], ssum[2][4];
  f32x4 accO[2][4];
#pragma unroll
  for (int qi = 0; qi < 2; ++qi)
#pragma unroll
    for (int r = 0; r < 4; ++r) { mrun[qi][r] = -3e38f; ssum[qi][r] = 0.f; }
#pragma unroll
  for (int qi = 0; qi < 2; ++qi)
#pragma unroll
    for (int vj = 0; vj < 4; ++vj) accO[qi][vj] = (f32x4){0.f, 0.f, 0.f, 0.f};

  for (int kt = 0; kt < NN / 64; ++kt) {
    const int k0 = kt * 64;
    __syncthreads();
#pragma unroll
    for (int e = 0; e < 2; ++e) {  // stage K 64x64
      const int c = tid + e * 256;
      const int row = c >> 3, c8 = c & 7;
      *(s16x8*)&ldsK[row * 72 + c8 * 8] = *(const s16x8*)&Kp[(k0 + row) * HD + c8 * 8];
    }
#pragma unroll
    for (int e = 0; e < 16; ++e) {  // stage V transposed
      const int f = tid + e * 256;
      const int k = f >> 6, d = f & 63;
      ldsVt[d * 72 + k] = Vp[(k0 + k) * HD + d];
    }
    __syncthreads();

    // S = Q K^T
    f32x4 accS[2][4];
#pragma unroll
    for (int qi = 0; qi < 2; ++qi)
#pragma unroll
      for (int kj = 0; kj < 4; ++kj) accS[qi][kj] = (f32x4){0.f, 0.f, 0.f, 0.f};
#pragma unroll
    for (int kj = 0; kj < 4; ++kj) {
      s16x8 b0 = *(const s16x8*)&ldsK[(kj * 16 + rowf) * 72 + kg * 8];
      s16x8 b1 = *(const s16x8*)&ldsK[(kj * 16 + rowf) * 72 + 32 + kg * 8];
#pragma unroll
      for (int qi = 0; qi < 2; ++qi) {
        accS[qi][kj] = mfma16(aQ[qi][0], b0, accS[qi][kj]);
        accS[qi][kj] = mfma16(aQ[qi][1], b1, accS[qi][kj]);
      }
    }

    // mask + online softmax; write P (bf16) to wave-private LDS
#pragma unroll
    for (int qi = 0; qi < 2; ++qi) {
      float pv[4][4];
#pragma unroll
      for (int r = 0; r < 4; ++r) {
        const int q = wq + qi * 16 + kg * 4 + r;
        const unsigned m0w = mw[(b * NN + q) * (NN / 32) + kt * 2];
        const unsigned m1w = mw[(b * NN + q) * (NN / 32) + kt * 2 + 1];
#pragma unroll
        for (int kj = 0; kj < 4; ++kj) {
          float s = accS[qi][kj][r] * 0.125f;  // 1/sqrt(64)
          const unsigned wd = (kj & 2) ? m1w : m0w;
          if ((wd >> ((kj & 1) * 16 + rowf)) & 1u) s = -1e30f;
          pv[r][kj] = s;
        }
      }
#pragma unroll
      for (int r = 0; r < 4; ++r) {
        float tm = fmaxf(fmaxf(pv[r][0], pv[r][1]), fmaxf(pv[r][2], pv[r][3]));
        tm = fmaxf(tm, __shfl_xor(tm, 1));
        tm = fmaxf(tm, __shfl_xor(tm, 2));
        tm = fmaxf(tm, __shfl_xor(tm, 4));
        tm = fmaxf(tm, __shfl_xor(tm, 8));
        const float mn = fmaxf(mrun[qi][r], tm);
        const float alpha = __expf(mrun[qi][r] - mn);
        mrun[qi][r] = mn;
        float ps = 0.f;
#pragma unroll
        for (int kj = 0; kj < 4; ++kj) {
          const float p = __expf(pv[r][kj] - mn);
          ps += p;
          ldsP[(w * 32 + qi * 16 + kg * 4 + r) * 72 + kj * 16 + rowf] = f2bf(p);
        }
        // FIX: row sum must be reduced across the 16 lanes of this row group
        ps += __shfl_xor(ps, 1);
        ps += __shfl_xor(ps, 2);
        ps += __shfl_xor(ps, 4);
        ps += __shfl_xor(ps, 8);
        ssum[qi][r] = ssum[qi][r] * alpha + ps;
#pragma unroll
        for (int vj = 0; vj < 4; ++vj) accO[qi][vj][r] *= alpha;
      }
    }
    __syncthreads();  // P visible (conservative: also orders vs. next restage)

    // O += P @ V
#pragma unroll
    for (int kk = 0; kk < 2; ++kk) {
      s16x8 aP0 = *(const s16x8*)&ldsP[(w * 32 + rowf) * 72 + kk * 32 + kg * 8];
      s16x8 aP1 = *(const s16x8*)&ldsP[(w * 32 + 16 + rowf) * 72 + kk * 32 + kg * 8];
#pragma unroll
      for (int vj = 0; vj < 4; ++vj) {
        s16x8 bV = *(const s16x8*)&ldsVt[(vj * 16 + rowf) * 72 + kk * 32 + kg * 8];
        accO[0][vj] = mfma16(aP0, bV, accO[0][vj]);
        accO[1][vj] = mfma16(aP1, bV, accO[1][vj]);
      }
    }
  }

  // heads[b][q][h][v] = O / ssum
#pragma unroll
  for (int qi = 0; qi < 2; ++qi) {
    float rc[4];
#pragma unroll
    for (int r = 0; r < 4; ++r) rc[r] = 1.0f / ssum[qi][r];
#pragma unroll
    for (int vj = 0; vj < 4; ++vj)
#pragma unroll
      for (int r = 0; r < 4; ++r) {
        const int q = wq + qi * 16 + kg * 4 + r;
        heads[((size_t)(b * NN + q) * HH + h) * HD + vj * 16 + rowf] =
            f2bf(accO[qi][vj][r] * rc[r]);
      }
  }
}

// ---- output GEMM: out(16384 x 512) = heads(16384 x 512) @ Wo(512 x 512), fp32 out ----
__global__ __launch_bounds__(256) void k_out(
    const s16x8* __restrict__ A8, const short* __restrict__ Wo, float* __restrict__ out) {
  __shared__ short ldsA[128 * 72];
  __shared__ short ldsBt[64 * 72];
  const int tid = threadIdx.x;
  const int m0 = blockIdx.x * 128;
  const int n0 = blockIdx.y * 64;
  const int w = tid >> 6, l = tid & 63, rowf = l & 15, kg = l >> 4;

  f32x4 acc[2][4];
#pragma unroll
  for (int qi = 0; qi < 2; ++qi)
#pragma unroll
    for (int cj = 0; cj < 4; ++cj) acc[qi][cj] = (f32x4){0.f, 0.f, 0.f, 0.f};

  for (int kt = 0; kt < DIN / 64; ++kt) {
    const int k0 = kt * 64;
    __syncthreads();
#pragma unroll
    for (int e = 0; e < 4; ++e) {
      const int c = tid + e * 256;
      const int row = c >> 3, c8 = c & 7;
      *(s16x8*)&ldsA[row * 72 + c8 * 8] = A8[(m0 + row) * (DIN / 8) + (k0 >> 3) + c8];
    }
#pragma unroll
    for (int e = 0; e < 16; ++e) {
      const int f = tid + e * 256;
      const int k = f >> 6, n = f & 63;
      ldsBt[n * 72 + k] = Wo[(k0 + k) * DIN + n0 + n];
    }
    __syncthreads();

    s16x8 af[2][2], bfr[4][2];
#pragma unroll
    for (int qi = 0; qi < 2; ++qi)
#pragma unroll
      for (int kk = 0; kk < 2; ++kk)
        af[qi][kk] = *(const s16x8*)&ldsA[(w * 32 + qi * 16 + rowf) * 72 + kk * 32 + kg * 8];
#pragma unroll
    for (int cj = 0; cj < 4; ++cj)
#pragma unroll
      for (int kk = 0; kk < 2; ++kk)
        bfr[cj][kk] = *(const s16x8*)&ldsBt[(cj * 16 + rowf) * 72 + kk * 32 + kg * 8];
#pragma unroll
    for (int kk = 0; kk < 2; ++kk)
#pragma unroll
      for (int qi = 0; qi < 2; ++qi)
#pragma unroll
        for (int cj = 0; cj < 4; ++cj)
          acc[qi][cj] = mfma16(af[qi][kk], bfr[cj][kk], acc[qi][cj]);
  }

#pragma unroll
  for (int qi = 0; qi < 2; ++qi)
#pragma unroll
    for (int cj = 0; cj < 4; ++cj)
#pragma unroll
      for (int r = 0; r < 4; ++r) {
        const int m = m0 + w * 32 + qi * 16 + kg * 4 + r;
        out[(size_t)m * DIN + n0 + cj * 16 + rowf] = acc[qi][cj][r];
      }
}

extern "C" void kernel_launch(void* const* d_in, const int* in_sizes, int n_in,
                              void* d_out, int out_size, void* d_ws, size_t ws_size,
                              hipStream_t stream) {
  if (n_in < 6) return;
  const float* q  = (const float*)d_in[0];
  const void*  mk = d_in[1];
  const float* Wq = (const float*)d_in[2];
  const float* Wk = (const float*)d_in[3];
  const float* Wv = (const float*)d_in[4];
  const float* Wo = (const float*)d_in[5];
  float* out = (float*)d_out;

  char* ws = (char*)d_ws;
  size_t o = 0;
  auto alloc = [&](size_t sz) { char* p = ws + o; o = (o + sz + 255) & ~(size_t)255; return p; };
  int*                flag   = (int*)alloc(4);
  unsigned long long* mwords = (unsigned long long*)alloc((size_t)BB * NN * NN / 8);
  short* qbf   = (short*)alloc((size_t)BB * NN * DIN * 2);
  short* wqb   = (short*)alloc((size_t)HH * DIN * HD * 2);
  short* wkb   = (short*)alloc((size_t)HH * DIN * HD * 2);
  short* wvb   = (short*)alloc((size_t)HH * DIN * HD * 2);
  short* wob   = (short*)alloc((size_t)HH * HD * DIN * 2);
  short* Qbuf  = (short*)alloc((size_t)HH * BB * NN * HD * 2);
  short* Kbuf  = (short*)alloc((size_t)HH * BB * NN * HD * 2);
  short* Vbuf  = (short*)alloc((size_t)HH * BB * NN * HD * 2);
  short* heads = (short*)alloc((size_t)BB * NN * HH * HD * 2);
  if (o > ws_size) return;  // workspace too small: bail (output stays zero)

  k_detect<<<1, 256, 0, stream>>>((const unsigned char*)mk, flag);
  k_packmask<<<(BB * NN * NN) / 256, 256, 0, stream>>>(mk, flag, mwords);
  k_f2bf8<<<(BB * NN * DIN / 8) / 256, 256, 0, stream>>>(q, qbf, BB * NN * DIN / 8);
  k_f2bf8<<<(HH * DIN * HD / 8) / 256, 256, 0, stream>>>(Wq, wqb, HH * DIN * HD / 8);
  k_f2bf8<<<(HH * DIN * HD / 8) / 256, 256, 0, stream>>>(Wk, wkb, HH * DIN * HD / 8);
  k_f2bf8<<<(HH * DIN * HD / 8) / 256, 256, 0, stream>>>(Wv, wvb, HH * DIN * HD / 8);
  k_f2bf8<<<(HH * HD * DIN / 8) / 256, 256, 0, stream>>>(Wo, wob, HH * HD * DIN / 8);
  k_proj<<<dim3(BB * NN / 128, 24), 256, 0, stream>>>((const s16x8*)qbf, wqb, wkb, wvb,
                                                      Qbuf, Kbuf, Vbuf);
  k_attn<<<dim3(NN / 128, BB, HH), 256, 0, stream>>>(Qbuf, Kbuf, Vbuf,
                                                     (const unsigned int*)mwords, heads);
  k_out<<<dim3(BB * NN / 128, DIN / 64), 256, 0, stream>>>((const s16x8*)heads, wob, out);
}

// Round 3
// 217.758 us; speedup vs baseline: 1.2245x; 1.2245x over previous
//
#include <hip/hip_runtime.h>
#include <hip/hip_bf16.h>

#define HH 8
#define DIN 512
#define HD 64
#define BB 16
#define NN 1024

typedef float f32x4 __attribute__((ext_vector_type(4)));
typedef short s16x8 __attribute__((ext_vector_type(8)));
typedef __bf16 bf16x8 __attribute__((ext_vector_type(8)));

__device__ __forceinline__ short f2bf(float f) {
  union { float f; unsigned u; } v; v.f = f;
  unsigned r = v.u + 0x7FFFu + ((v.u >> 16) & 1u);  // RNE
  return (short)(r >> 16);
}

__device__ __forceinline__ f32x4 mfma16(s16x8 a, s16x8 b, f32x4 c) {
  return __builtin_amdgcn_mfma_f32_16x16x32_bf16(
      __builtin_bit_cast(bf16x8, a), __builtin_bit_cast(bf16x8, b), c, 0, 0, 0);
}

// ---- mask dtype detection: 4-byte storage has byte(%4==1)==0 always ----
__global__ void k_detect(const unsigned char* __restrict__ m, int* __restrict__ flag) {
  const int t = threadIdx.x;
  const int nz = (m[4 * t + 1] != 0);
  unsigned long long b = __ballot(nz);
  __shared__ unsigned int anyv;
  if (t == 0) anyv = 0u;
  __syncthreads();
  if ((t & 63) == 0 && b) atomicOr(&anyv, 1u);
  __syncthreads();
  if (t == 0) flag[0] = (int)anyv;  // 1 = byte storage, 0 = 4-byte storage
}

// ---- pack mask to bits: bit=1 means masked (not allowed) ----
__global__ void k_packmask(const void* __restrict__ mask, const int* __restrict__ flag,
                           unsigned long long* __restrict__ words64) {
  const int i = blockIdx.x * 256 + threadIdx.x;
  int v;
  if (flag[0])
    v = (((const unsigned char*)mask)[i] != 0);
  else
    v = (((const int*)mask)[i] != 0);
  unsigned long long b = __ballot(v);
  if ((threadIdx.x & 63) == 0) words64[i >> 6] = b;
}

// ---- fp32 -> bf16, 8 elems/thread ----
__global__ void k_f2bf8(const float* __restrict__ src, short* __restrict__ dst, int n8) {
  const int i = blockIdx.x * 256 + threadIdx.x;
  if (i >= n8) return;
  const float4* s4 = (const float4*)src;
  float4 a = s4[2 * i], c = s4[2 * i + 1];
  s16x8 o;
  o[0] = f2bf(a.x); o[1] = f2bf(a.y); o[2] = f2bf(a.z); o[3] = f2bf(a.w);
  o[4] = f2bf(c.x); o[5] = f2bf(c.y); o[6] = f2bf(c.z); o[7] = f2bf(c.w);
  ((s16x8*)dst)[i] = o;
}

// ---- QKV projection. Q (mat 0): pre-scaled by 1/8, layout [h][b][n][d].
//      K (mat 1): [h][b][n][d].  V (mat 2): TRANSPOSED output [h][b][v][n]. ----
__global__ __launch_bounds__(256) void k_proj(
    const s16x8* __restrict__ A8, const short* __restrict__ Wq,
    const short* __restrict__ Wk, const short* __restrict__ Wv,
    short* __restrict__ Qb, short* __restrict__ Kb, short* __restrict__ VtG) {
  __shared__ short ldsA[128 * 72];
  __shared__ short ldsBt[64 * 72];   // Bt[n][k] = W[k][n]
  const int tid = threadIdx.x;
  const int m0 = blockIdx.x * 128;
  const int j = blockIdx.y;
  const int mat = j >> 3, head = j & 7;
  const short* Wbase = (mat == 0 ? Wq : (mat == 1 ? Wk : Wv)) + head * (DIN * HD);
  const int w = tid >> 6, l = tid & 63, rowf = l & 15, kg = l >> 4;

  f32x4 acc[2][4];
#pragma unroll
  for (int qi = 0; qi < 2; ++qi)
#pragma unroll
    for (int cj = 0; cj < 4; ++cj) acc[qi][cj] = (f32x4){0.f, 0.f, 0.f, 0.f};

  for (int kt = 0; kt < DIN / 64; ++kt) {
    const int k0 = kt * 64;
    __syncthreads();
#pragma unroll
    for (int e = 0; e < 4; ++e) {
      const int c = tid + e * 256;
      const int row = c >> 3, c8 = c & 7;
      *(s16x8*)&ldsA[row * 72 + c8 * 8] = A8[(m0 + row) * (DIN / 8) + (k0 >> 3) + c8];
    }
#pragma unroll
    for (int e = 0; e < 16; ++e) {
      const int f = tid + e * 256;
      const int k = f >> 6, n = f & 63;
      ldsBt[n * 72 + k] = Wbase[(k0 + k) * HD + n];
    }
    __syncthreads();

    s16x8 af[2][2], bfr[4][2];
#pragma unroll
    for (int qi = 0; qi < 2; ++qi)
#pragma unroll
      for (int kk = 0; kk < 2; ++kk)
        af[qi][kk] = *(const s16x8*)&ldsA[(w * 32 + qi * 16 + rowf) * 72 + kk * 32 + kg * 8];
#pragma unroll
    for (int cj = 0; cj < 4; ++cj)
#pragma unroll
      for (int kk = 0; kk < 2; ++kk)
        bfr[cj][kk] = *(const s16x8*)&ldsBt[(cj * 16 + rowf) * 72 + kk * 32 + kg * 8];
    if (mat == 2) {
      // V^T = mfma(A=W^T-frag(bfr), B=q-frag(af)) -> D[v][n]
#pragma unroll
      for (int kk = 0; kk < 2; ++kk)
#pragma unroll
        for (int qi = 0; qi < 2; ++qi)
#pragma unroll
          for (int cj = 0; cj < 4; ++cj)
            acc[qi][cj] = mfma16(bfr[cj][kk], af[qi][kk], acc[qi][cj]);
    } else {
#pragma unroll
      for (int kk = 0; kk < 2; ++kk)
#pragma unroll
        for (int qi = 0; qi < 2; ++qi)
#pragma unroll
          for (int cj = 0; cj < 4; ++cj)
            acc[qi][cj] = mfma16(af[qi][kk], bfr[cj][kk], acc[qi][cj]);
    }
  }

  if (mat == 2) {
    const int bb = m0 >> 10, nbase = (m0 & 1023) + w * 32;
    short* Vt = VtG + ((size_t)(head * BB + bb)) * HD * NN;
#pragma unroll
    for (int qi = 0; qi < 2; ++qi)
#pragma unroll
      for (int cj = 0; cj < 4; ++cj)
#pragma unroll
        for (int r = 0; r < 4; ++r) {
          const int v = cj * 16 + kg * 4 + r;
          const int n = nbase + qi * 16 + rowf;
          Vt[(size_t)v * NN + n] = f2bf(acc[qi][cj][r]);
        }
  } else {
    short* Ob = (mat == 0 ? Qb : Kb) + head * (BB * NN * HD);
    const float sc = (mat == 0) ? 0.125f : 1.0f;  // fold 1/sqrt(64) into Q (exact)
#pragma unroll
    for (int qi = 0; qi < 2; ++qi)
#pragma unroll
      for (int cj = 0; cj < 4; ++cj)
#pragma unroll
        for (int r = 0; r < 4; ++r) {
          const int m = m0 + w * 32 + qi * 16 + kg * 4 + r;
          Ob[(size_t)m * HD + cj * 16 + rowf] = f2bf(acc[qi][cj][r] * sc);
        }
  }
}

// ---- flash attention, S^T formulation. block = (h,b,128 q), 4 waves x 32 q ----
// S^T = mfma(K-frag, Q-frag): lane rowf = q, D rows = keys (permuted staging).
// P stays lane-local; PV: O^T = mfma(Vt-frag, P-frag). Vt comes pre-transposed.
__global__ __launch_bounds__(256) void k_attn(
    const short* __restrict__ Qb, const short* __restrict__ Kb, const short* __restrict__ VtG,
    const unsigned int* __restrict__ mw, short* __restrict__ heads) {
  __shared__ short smem[2 * 64 * 72];  // [0]: K tile (key-permuted rows), [1]: Vt tile
  short* ldsK = smem;
  short* ldsVt = smem + 64 * 72;
  const int tid = threadIdx.x;
  const int w = tid >> 6, l = tid & 63, rowf = l & 15, kg = l >> 4;
  const int qblk = blockIdx.x, b = blockIdx.y, h = blockIdx.z;
  const int hb = (h * BB + b) * NN;
  const short* Qp = Qb + (size_t)hb * HD;
  const short* Kp = Kb + (size_t)hb * HD;
  const short* Vtp = VtG + (size_t)(h * BB + b) * HD * NN;  // [v][n]
  const int wq = qblk * 128 + w * 32;

  // Q as B-frags (lane rowf = q)
  s16x8 bQ[2][2];
#pragma unroll
  for (int qi = 0; qi < 2; ++qi)
#pragma unroll
    for (int kk = 0; kk < 2; ++kk)
      bQ[qi][kk] = *(const s16x8*)&Qp[(wq + qi * 16 + rowf) * HD + kk * 32 + kg * 8];

  float mrun[2] = {-3e38f, -3e38f}, ssum[2] = {0.f, 0.f};
  f32x4 accO[2][4];  // O^T: [qi][vj], col q = rowf, row v = vj*16+kg*4+r
#pragma unroll
  for (int qi = 0; qi < 2; ++qi)
#pragma unroll
    for (int vj = 0; vj < 4; ++vj) accO[qi][vj] = (f32x4){0.f, 0.f, 0.f, 0.f};

  // staging addresses (2 chunks each of K and Vt per thread)
  const int kr0 = tid >> 3, kr1 = (tid >> 3) + 32, c8 = (tid & 7) * 8;
  // K LDS row permutation: key -> m*16+i with key=(m>>1)*32+(i>>2)*8+(m&1)*4+(i&3)
  auto ldsrow = [](int key) {
    const int m = ((key >> 5) << 1) | ((key >> 2) & 1);
    const int i = (((key >> 3) & 3) << 2) | (key & 3);
    return m * 16 + i;
  };
  const int dK0 = ldsrow(kr0) * 72 + c8, dK1 = ldsrow(kr1) * 72 + c8;
  const int dV0 = kr0 * 72 + c8, dV1 = kr1 * 72 + c8;

  // prologue: load tile 0
  s16x8 rk0 = *(const s16x8*)&Kp[kr0 * HD + c8];
  s16x8 rk1 = *(const s16x8*)&Kp[kr1 * HD + c8];
  s16x8 rv0 = *(const s16x8*)&Vtp[(size_t)kr0 * NN + c8];
  s16x8 rv1 = *(const s16x8*)&Vtp[(size_t)kr1 * NN + c8];

  const unsigned int* mrow0 = mw + (size_t)(b * NN + wq + rowf) * 32;

  for (int kt = 0; kt < NN / 64; ++kt) {
    __syncthreads();  // previous tile's compute done
    *(s16x8*)&ldsK[dK0] = rk0;
    *(s16x8*)&ldsK[dK1] = rk1;
    *(s16x8*)&ldsVt[dV0] = rv0;
    *(s16x8*)&ldsVt[dV1] = rv1;
    if (kt + 1 < NN / 64) {  // T14: issue next-tile loads; they complete under compute
      const int kn = (kt + 1) * 64;
      rk0 = *(const s16x8*)&Kp[(kn + kr0) * HD + c8];
      rk1 = *(const s16x8*)&Kp[(kn + kr1) * HD + c8];
      rv0 = *(const s16x8*)&Vtp[(size_t)kr0 * NN + kn + c8];
      rv1 = *(const s16x8*)&Vtp[(size_t)kr1 * NN + kn + c8];
    }
    __syncthreads();  // tile staged

    // S^T: accS[qi][m], D row (kg*4+r) of block m = key (m>>1)*32+kg*8+(m&1)*4+r
    f32x4 accS[2][4];
#pragma unroll
    for (int m = 0; m < 4; ++m) {
      s16x8 a0 = *(const s16x8*)&ldsK[(m * 16 + rowf) * 72 + kg * 8];
      s16x8 a1 = *(const s16x8*)&ldsK[(m * 16 + rowf) * 72 + 32 + kg * 8];
      accS[0][m] = mfma16(a0, bQ[0][0], (f32x4){0.f, 0.f, 0.f, 0.f});
      accS[0][m] = mfma16(a1, bQ[0][1], accS[0][m]);
      accS[1][m] = mfma16(a0, bQ[1][0], (f32x4){0.f, 0.f, 0.f, 0.f});
      accS[1][m] = mfma16(a1, bQ[1][1], accS[1][m]);
    }

    s16x8 pa[2][2];  // P frags per qi, per kk
#pragma unroll
    for (int qi = 0; qi < 2; ++qi) {
      const unsigned int* mword = mrow0 + qi * 16 * 32 + kt * 2;
      const unsigned u0 = mword[0] >> (kg * 8);
      const unsigned u1 = mword[1] >> (kg * 8);
      // raw-score max (mask not applied: larger max only rescales, cancels in norm)
      float tmax = -3e38f;
#pragma unroll
      for (int m = 0; m < 4; ++m)
#pragma unroll
        for (int r = 0; r < 4; ++r) tmax = fmaxf(tmax, accS[qi][m][r]);
      tmax = fmaxf(tmax, __shfl_xor(tmax, 16));
      tmax = fmaxf(tmax, __shfl_xor(tmax, 32));
      const float mn = fmaxf(mrun[qi], tmax);
      const float alpha = __expf(mrun[qi] - mn);
      mrun[qi] = mn;
      float ps = 0.f;
      short pel[16];
#pragma unroll
      for (int m = 0; m < 4; ++m) {
        const unsigned u = (m < 2) ? u0 : u1;
#pragma unroll
        for (int r = 0; r < 4; ++r) {
          float p = __expf(accS[qi][m][r] - mn);
          p = ((u >> ((m & 1) * 4 + r)) & 1u) ? 0.f : p;  // zero masked (post-exp)
          ps += p;
          pel[m * 4 + r] = f2bf(p);
        }
      }
      ps += __shfl_xor(ps, 16);
      ps += __shfl_xor(ps, 32);
      ssum[qi] = ssum[qi] * alpha + ps;
#pragma unroll
      for (int vj = 0; vj < 4; ++vj)
#pragma unroll
        for (int r = 0; r < 4; ++r) accO[qi][vj][r] *= alpha;
      // pel[m*4+r] -> frag kk element j: key kk*32+kg*8+j  (j = (m&1)*4+r)
#pragma unroll
      for (int kk = 0; kk < 2; ++kk) {
        s16x8 f;
#pragma unroll
        for (int jj = 0; jj < 8; ++jj) f[jj] = pel[kk * 8 + jj];
        pa[qi][kk] = f;
      }
    }

    // O^T += mfma(Vt-frag, P-frag)
#pragma unroll
    for (int kk = 0; kk < 2; ++kk)
#pragma unroll
      for (int vj = 0; vj < 4; ++vj) {
        s16x8 aV = *(const s16x8*)&ldsVt[(vj * 16 + rowf) * 72 + kk * 32 + kg * 8];
        accO[0][vj] = mfma16(aV, pa[0][kk], accO[0][vj]);
        accO[1][vj] = mfma16(aV, pa[1][kk], accO[1][vj]);
      }
  }

  // epilogue: per-wave LDS transpose O^T -> [q][v], then coalesced global store
  __syncthreads();  // all waves done reading K/V tiles
  short* tb = smem + w * (32 * 72);
  {
    const float rc0 = 1.0f / ssum[0], rc1 = 1.0f / ssum[1];
#pragma unroll
    for (int qi = 0; qi < 2; ++qi) {
      const float rc = qi ? rc1 : rc0;
#pragma unroll
      for (int vj = 0; vj < 4; ++vj)
#pragma unroll
        for (int r = 0; r < 4; ++r)
          tb[(qi * 16 + rowf) * 72 + vj * 16 + kg * 4 + r] = f2bf(accO[qi][vj][r] * rc);
    }
  }
  // wave-private region: LDS dependency handled by waitcnt, no barrier needed
#pragma unroll
  for (int it = 0; it < 4; ++it) {
    const int ql = (l >> 3) + it * 8, oct = l & 7;
    s16x8 v = *(const s16x8*)&tb[ql * 72 + oct * 8];
    *(s16x8*)&heads[((size_t)(b * NN + qblk * 128 + w * 32 + ql) * HH + h) * HD + oct * 8] = v;
  }
}

// ---- output GEMM: out(16384 x 512) = heads(16384 x 512) @ Wo(512 x 512), fp32 out ----
__global__ __launch_bounds__(256) void k_out(
    const s16x8* __restrict__ A8, const short* __restrict__ Wo, float* __restrict__ out) {
  __shared__ short ldsA[128 * 72];
  __shared__ short ldsBt[64 * 72];
  const int tid = threadIdx.x;
  const int m0 = blockIdx.x * 128;
  const int n0 = blockIdx.y * 64;
  const int w = tid >> 6, l = tid & 63, rowf = l & 15, kg = l >> 4;

  f32x4 acc[2][4];
#pragma unroll
  for (int qi = 0; qi < 2; ++qi)
#pragma unroll
    for (int cj = 0; cj < 4; ++cj) acc[qi][cj] = (f32x4){0.f, 0.f, 0.f, 0.f};

  for (int kt = 0; kt < DIN / 64; ++kt) {
    const int k0 = kt * 64;
    __syncthreads();
#pragma unroll
    for (int e = 0; e < 4; ++e) {
      const int c = tid + e * 256;
      const int row = c >> 3, c8 = c & 7;
      *(s16x8*)&ldsA[row * 72 + c8 * 8] = A8[(m0 + row) * (DIN / 8) + (k0 >> 3) + c8];
    }
#pragma unroll
    for (int e = 0; e < 16; ++e) {
      const int f = tid + e * 256;
      const int k = f >> 6, n = f & 63;
      ldsBt[n * 72 + k] = Wo[(k0 + k) * DIN + n0 + n];
    }
    __syncthreads();

    s16x8 af[2][2], bfr[4][2];
#pragma unroll
    for (int qi = 0; qi < 2; ++qi)
#pragma unroll
      for (int kk = 0; kk < 2; ++kk)
        af[qi][kk] = *(const s16x8*)&ldsA[(w * 32 + qi * 16 + rowf) * 72 + kk * 32 + kg * 8];
#pragma unroll
    for (int cj = 0; cj < 4; ++cj)
#pragma unroll
      for (int kk = 0; kk < 2; ++kk)
        bfr[cj][kk] = *(const s16x8*)&ldsBt[(cj * 16 + rowf) * 72 + kk * 32 + kg * 8];
#pragma unroll
    for (int kk = 0; kk < 2; ++kk)
#pragma unroll
      for (int qi = 0; qi < 2; ++qi)
#pragma unroll
        for (int cj = 0; cj < 4; ++cj)
          acc[qi][cj] = mfma16(af[qi][kk], bfr[cj][kk], acc[qi][cj]);
  }

#pragma unroll
  for (int qi = 0; qi < 2; ++qi)
#pragma unroll
    for (int cj = 0; cj < 4; ++cj)
#pragma unroll
      for (int r = 0; r < 4; ++r) {
        const int m = m0 + w * 32 + qi * 16 + kg * 4 + r;
        out[(size_t)m * DIN + n0 + cj * 16 + rowf] = acc[qi][cj][r];
      }
}

extern "C" void kernel_launch(void* const* d_in, const int* in_sizes, int n_in,
                              void* d_out, int out_size, void* d_ws, size_t ws_size,
                              hipStream_t stream) {
  if (n_in < 6) return;
  const float* q  = (const float*)d_in[0];
  const void*  mk = d_in[1];
  const float* Wq = (const float*)d_in[2];
  const float* Wk = (const float*)d_in[3];
  const float* Wv = (const float*)d_in[4];
  const float* Wo = (const float*)d_in[5];
  float* out = (float*)d_out;

  char* ws = (char*)d_ws;
  size_t o = 0;
  auto alloc = [&](size_t sz) { char* p = ws + o; o = (o + sz + 255) & ~(size_t)255; return p; };
  int*                flag   = (int*)alloc(4);
  unsigned long long* mwords = (unsigned long long*)alloc((size_t)BB * NN * NN / 8);
  short* qbf   = (short*)alloc((size_t)BB * NN * DIN * 2);
  short* wqb   = (short*)alloc((size_t)HH * DIN * HD * 2);
  short* wkb   = (short*)alloc((size_t)HH * DIN * HD * 2);
  short* wvb   = (short*)alloc((size_t)HH * DIN * HD * 2);
  short* wob   = (short*)alloc((size_t)HH * HD * DIN * 2);
  short* Qbuf  = (short*)alloc((size_t)HH * BB * NN * HD * 2);
  short* Kbuf  = (short*)alloc((size_t)HH * BB * NN * HD * 2);
  short* VtBuf = (short*)alloc((size_t)HH * BB * HD * NN * 2);
  short* heads = (short*)alloc((size_t)BB * NN * HH * HD * 2);
  if (o > ws_size) return;

  k_detect<<<1, 256, 0, stream>>>((const unsigned char*)mk, flag);
  k_packmask<<<(BB * NN * NN) / 256, 256, 0, stream>>>(mk, flag, mwords);
  k_f2bf8<<<(BB * NN * DIN / 8) / 256, 256, 0, stream>>>(q, qbf, BB * NN * DIN / 8);
  k_f2bf8<<<(HH * DIN * HD / 8) / 256, 256, 0, stream>>>(Wq, wqb, HH * DIN * HD / 8);
  k_f2bf8<<<(HH * DIN * HD / 8) / 256, 256, 0, stream>>>(Wk, wkb, HH * DIN * HD / 8);
  k_f2bf8<<<(HH * DIN * HD / 8) / 256, 256, 0, stream>>>(Wv, wvb, HH * DIN * HD / 8);
  k_f2bf8<<<(HH * HD * DIN / 8) / 256, 256, 0, stream>>>(Wo, wob, HH * HD * DIN / 8);
  k_proj<<<dim3(BB * NN / 128, 24), 256, 0, stream>>>((const s16x8*)qbf, wqb, wkb, wvb,
                                                      Qbuf, Kbuf, VtBuf);
  k_attn<<<dim3(NN / 128, BB, HH), 256, 0, stream>>>(Qbuf, Kbuf, VtBuf,
                                                     (const unsigned int*)mwords, heads);
  k_out<<<dim3(BB * NN / 128, DIN / 64), 256, 0, stream>>>((const s16x8*)heads, wob, out);
}